// Round 3
// baseline (1465.415 us; speedup 1.0000x reference)
//
#include <hip/hip_runtime.h>
#include <hip/hip_bf16.h>
#include <cstdint>
#include <cstddef>

// ---------------- JAX threefry2x32 (partitionable scheme) — FROZEN (verified R1)
struct TF2 { uint32_t a, b; };

__host__ __device__ constexpr uint32_t rotl32(uint32_t v, int r) {
  return (v << r) | (v >> (32 - r));
}

__host__ __device__ constexpr TF2 threefry2x32(uint32_t k0, uint32_t k1,
                                               uint32_t x0, uint32_t x1) {
  uint32_t ks0 = k0, ks1 = k1, ks2 = k0 ^ k1 ^ 0x1BD11BDAu;
  const int rotA[4] = {13, 15, 26, 6};
  const int rotB[4] = {17, 29, 16, 24};
  x0 += ks0; x1 += ks1;
  for (int i = 0; i < 5; ++i) {
    const int* rot = (i % 2 == 0) ? rotA : rotB;
    for (int j = 0; j < 4; ++j) {
      x0 += x1; x1 = rotl32(x1, rot[j]); x1 ^= x0;
    }
    uint32_t ks[3] = {ks0, ks1, ks2};
    x0 += ks[(i + 1) % 3];
    x1 += ks[(i + 2) % 3] + (uint32_t)(i + 1);
  }
  return TF2{x0, x1};
}

__device__ __forceinline__ float jax_mask(uint32_t child, uint32_t idx) {
  TF2 ck = threefry2x32(0u, 42u, 0u, child);   // constant-folds
  TF2 r  = threefry2x32(ck.a, ck.b, 0u, idx);
  uint32_t bits = r.a ^ r.b;
  float u = __uint_as_float((bits >> 9) | 0x3f800000u) - 1.0f;
  return (u < 0.7f) ? (1.0f / 0.7f) : 0.0f;
}

__device__ __forceinline__ unsigned short f2bf(float f) {
  uint32_t u = __float_as_uint(f);
  uint32_t r = (u + 0x7fffu + ((u >> 16) & 1u)) >> 16;   // RNE
  return (unsigned short)r;
}
__device__ __forceinline__ float bf2f(unsigned short h) {
  return __uint_as_float((uint32_t)h << 16);
}

typedef __attribute__((ext_vector_type(8))) short short8;
typedef __attribute__((ext_vector_type(4))) float f32x4;

__device__ __forceinline__ void async_copy16(const unsigned short* g, unsigned short* l) {
  __builtin_amdgcn_global_load_lds(
      (const __attribute__((address_space(1))) unsigned int*)g,
      (__attribute__((address_space(3))) unsigned int*)l, 16, 0, 0);
}

// ---------------- build x (bf16) = [image_emb ; emb_table[targets]*word_mask]
__global__ __launch_bounds__(256) void build_x_kernel(
    const float* __restrict__ img, const int* __restrict__ tgt,
    const float* __restrict__ emb, unsigned short* __restrict__ x) {
  const int idx = blockIdx.x * 256 + threadIdx.x;   // b*32768 + t*512 + e
  const int e = idx & 511;
  const int t = (idx >> 9) & 63;
  const int b = idx >> 15;
  float v;
  if (t == 0) {
    v = img[b * 512 + e];
  } else {
    const int w = tgt[b * 64 + (t - 1)];
    const float wm = jax_mask(0u, (uint32_t)(b * 512 + e));
    v = emb[(size_t)w * 512 + e] * wm;
  }
  x[idx] = f2bf(v);
}

// ---------------- recurrent dropout masks (4,B,U), pre-scaled ------------
__global__ __launch_bounds__(256) void rec_mask_kernel(float* __restrict__ rm) {
  const int idx = blockIdx.x * 256 + threadIdx.x;
  rm[idx] = jax_mask(1u, (uint32_t)idx);
}

// ------- transpose+convert fp32 [R][C] -> bf16 [C][R] --------------------
__global__ __launch_bounds__(256) void transpose_cvt(
    const float* __restrict__ in, unsigned short* __restrict__ out,
    int R, int C) {
  __shared__ float tile[32][33];
  const int c0 = blockIdx.x * 32;
  const int r0 = blockIdx.y * 32;
  const int tx = threadIdx.x & 31;
  const int ty = threadIdx.x >> 5;
  for (int r = ty; r < 32; r += 8)
    tile[r][tx] = in[(size_t)(r0 + r) * C + (c0 + tx)];
  __syncthreads();
  for (int r = ty; r < 32; r += 8)
    out[(size_t)(c0 + r) * R + (r0 + tx)] = f2bf(tile[tx][r]);
}

// ------- split transpose: fp32 [R][C] -> bf16 hi/lo [C][R] ---------------
__global__ __launch_bounds__(256) void transpose_split(
    const float* __restrict__ in, unsigned short* __restrict__ oh,
    unsigned short* __restrict__ ol, int R, int C) {
  __shared__ float tile[32][33];
  const int c0 = blockIdx.x * 32;
  const int r0 = blockIdx.y * 32;
  const int tx = threadIdx.x & 31;
  const int ty = threadIdx.x >> 5;
  for (int r = ty; r < 32; r += 8)
    tile[r][tx] = in[(size_t)(r0 + r) * C + (c0 + tx)];
  __syncthreads();
  for (int r = ty; r < 32; r += 8) {
    const float v = tile[tx][r];
    const unsigned short hi = f2bf(v);
    const float lo = v - bf2f(hi);
    oh[(size_t)(c0 + r) * R + (r0 + tx)] = hi;
    ol[(size_t)(c0 + r) * R + (r0 + tx)] = f2bf(lo);
  }
}

// ---------------- bf16 MFMA GEMM: C[M][N] = A[M][512] * BT[N][512]^T + bias
// NOTE: m0 = blockIdx.x (fast) so consecutive blocks share the B tile (L2 reuse).
__global__ __launch_bounds__(256) void gemm_bf16_mfma(
    const unsigned short* __restrict__ A, const unsigned short* __restrict__ BT,
    const float* __restrict__ bias, float* __restrict__ C, int M, int N) {
  __shared__ unsigned short As[128 * 32];
  __shared__ unsigned short Bs[128 * 32];
  const int tid = threadIdx.x;
  const int lane = tid & 63;
  const int wave = tid >> 6;
  const int wm = (wave >> 1) * 64;
  const int wn = (wave & 1) * 64;
  const int m0 = blockIdx.x * 128;
  const int n0 = blockIdx.y * 128;

  f32x4 zero4 = {0.f, 0.f, 0.f, 0.f};
  f32x4 acc[4][4];
#pragma unroll
  for (int i = 0; i < 4; ++i)
#pragma unroll
    for (int j = 0; j < 4; ++j) acc[i][j] = zero4;

  const unsigned short* ga = A + (size_t)(m0 + (tid >> 2)) * 512 + (tid & 3) * 8;
  const unsigned short* gb = BT + (size_t)(n0 + (tid >> 2)) * 512 + (tid & 3) * 8;
  unsigned short* lwA = As + wave * 512;
  unsigned short* lwB = Bs + wave * 512;

  const int fr = lane & 15;
  const int kc = (lane >> 4) * 8;

  for (int k0 = 0; k0 < 512; k0 += 32) {
    __syncthreads();
    async_copy16(ga + k0, lwA);
    async_copy16(ga + k0 + 64 * 512, lwA + 2048);
    async_copy16(gb + k0, lwB);
    async_copy16(gb + k0 + 64 * 512, lwB + 2048);
    __syncthreads();

    short8 af[4], bf[4];
#pragma unroll
    for (int i = 0; i < 4; ++i)
      af[i] = *(const short8*)(As + (wm + i * 16 + fr) * 32 + kc);
#pragma unroll
    for (int i = 0; i < 4; ++i)
      bf[i] = *(const short8*)(Bs + (wn + i * 16 + fr) * 32 + kc);
#pragma unroll
    for (int mi = 0; mi < 4; ++mi)
#pragma unroll
      for (int ni = 0; ni < 4; ++ni)
        acc[mi][ni] = __builtin_amdgcn_mfma_f32_16x16x32_bf16(
            af[mi], bf[ni], acc[mi][ni], 0, 0, 0);
  }

#pragma unroll
  for (int mi = 0; mi < 4; ++mi) {
    const int mrow = m0 + wm + mi * 16 + (lane >> 4) * 4;
#pragma unroll
    for (int ni = 0; ni < 4; ++ni) {
      const int ncol = n0 + wn + ni * 16 + (lane & 15);
      const float bs = bias[ncol];
#pragma unroll
      for (int r2 = 0; r2 < 4; ++r2)
        C[(size_t)(mrow + r2) * N + ncol] = acc[mi][ni][r2] + bs;
    }
  }
}

// ---------------- persistent LSTM: all 64 steps, one launch ---------------
// 32 blocks x 256 threads; block owns u-range 16; wave g handles gate g.
// Recurrence GEMM in split-bf16 MFMA (hh+hl+lh -> ~fp32 accuracy).
// Masked-h state double-buffered in global (Abuf): parity p holds hi[65536]+lo[65536].
#define LSTM_BLOCKS 32

__global__ __launch_bounds__(256, 1) void lstm_persistent(
    const float* __restrict__ zin, const unsigned short* __restrict__ WrTh,
    const unsigned short* __restrict__ WrTl, const float* __restrict__ rm,
    unsigned short* __restrict__ Abuf, unsigned short* __restrict__ rnn,
    unsigned int* __restrict__ ctr) {
  __shared__ float zsh[4][32][17];
  const int tid = threadIdx.x;
  const int g = tid >> 6;            // wave = gate
  const int lane = tid & 63;
  const int fr = lane & 15;
  const int kq = (lane >> 4) * 8;
  const int u0 = blockIdx.x * 16;

  // hoist W_rec fragments for this wave's (gate, u-tile): 32 short8 = 128 VGPRs
  short8 wh[16], wl[16];
  {
    const unsigned short* bph = WrTh + ((size_t)(g * 512 + u0 + fr) * 512 + kq);
    const unsigned short* bpl = WrTl + ((size_t)(g * 512 + u0 + fr) * 512 + kq);
#pragma unroll
    for (int kk = 0; kk < 16; ++kk) {
      wh[kk] = *(const short8*)(bph + kk * 32);
      wl[kk] = *(const short8*)(bpl + kk * 32);
    }
  }

  // epilogue mapping: thread handles (b_0, ul) and (b_0+16, ul)
  const int b_0 = tid >> 4;          // 0..15
  const int ul = tid & 15;
  const int u = u0 + ul;
  float cst[2] = {0.f, 0.f};
  float rmv[2][4];
#pragma unroll
  for (int gg = 0; gg < 4; ++gg) {
    rmv[0][gg] = rm[(gg * 32 + b_0) * 512 + u];
    rmv[1][gg] = rm[(gg * 32 + b_0 + 16) * 512 + u];
  }

  const size_t aoff = (size_t)(g * 32 + fr) * 512 + kq;   // A-frag base (m-tile 0)

  for (int t = 0; t < 64; ++t) {
    const unsigned short* ar = Abuf + (size_t)(t & 1) * 131072;
    unsigned short* aw = Abuf + (size_t)((t & 1) ^ 1) * 131072;

    f32x4 acc0 = {0.f, 0.f, 0.f, 0.f};
    f32x4 acc1 = {0.f, 0.f, 0.f, 0.f};
#pragma unroll
    for (int kk = 0; kk < 16; ++kk) {
      const int off = kk * 32;
      const short8 ah0 = *(const short8*)(ar + aoff + off);
      const short8 al0 = *(const short8*)(ar + 65536 + aoff + off);
      const short8 ah1 = *(const short8*)(ar + aoff + 16 * 512 + off);
      const short8 al1 = *(const short8*)(ar + 65536 + aoff + 16 * 512 + off);
      acc0 = __builtin_amdgcn_mfma_f32_16x16x32_bf16(ah0, wh[kk], acc0, 0, 0, 0);
      acc0 = __builtin_amdgcn_mfma_f32_16x16x32_bf16(ah0, wl[kk], acc0, 0, 0, 0);
      acc0 = __builtin_amdgcn_mfma_f32_16x16x32_bf16(al0, wh[kk], acc0, 0, 0, 0);
      acc1 = __builtin_amdgcn_mfma_f32_16x16x32_bf16(ah1, wh[kk], acc1, 0, 0, 0);
      acc1 = __builtin_amdgcn_mfma_f32_16x16x32_bf16(ah1, wl[kk], acc1, 0, 0, 0);
      acc1 = __builtin_amdgcn_mfma_f32_16x16x32_bf16(al1, wh[kk], acc1, 0, 0, 0);
    }
    // z_rec -> LDS (C-layout: row m=(lane>>4)*4+r, col=lane&15)
    const int qm = (lane >> 4) * 4;
#pragma unroll
    for (int r = 0; r < 4; ++r) {
      zsh[g][qm + r][fr] = acc0[r];
      zsh[g][16 + qm + r][fr] = acc1[r];
    }
    __syncthreads();

#pragma unroll
    for (int half = 0; half < 2; ++half) {
      const int b = b_0 + half * 16;
      const float* zrow = zin + ((size_t)(b * 64 + t) * 2048 + u);
      const float zi = zrow[0]    + zsh[0][b][ul];
      const float zf = zrow[512]  + zsh[1][b][ul];
      const float zg = zrow[1024] + zsh[2][b][ul];
      const float zo = zrow[1536] + zsh[3][b][ul];
      const float i_ = 1.f / (1.f + expf(-zi));
      const float f_ = 1.f / (1.f + expf(-zf));
      const float g_ = tanhf(zg);
      const float o_ = 1.f / (1.f + expf(-zo));
      const float cn = f_ * cst[half] + i_ * g_;
      cst[half] = cn;
      const float hn = o_ * tanhf(cn);
      const float fm = jax_mask(2u, (uint32_t)((b * 64 + t) * 512 + u));
      rnn[(size_t)(b * 64 + t) * 512 + u] = f2bf(hn * fm);
#pragma unroll
      for (int gg = 0; gg < 4; ++gg) {
        const float hm = hn * rmv[half][gg];
        const unsigned short hi = f2bf(hm);
        const float lo = hm - bf2f(hi);
        const size_t o = (size_t)(gg * 32 + b) * 512 + u;
        aw[o] = hi;
        aw[65536 + o] = f2bf(lo);
      }
    }

    __threadfence();
    __syncthreads();
    if (tid == 0) {
      __hip_atomic_fetch_add(ctr, 1u, __ATOMIC_ACQ_REL, __HIP_MEMORY_SCOPE_AGENT);
      const unsigned int target = (unsigned int)(LSTM_BLOCKS * (t + 1));
      long guard = 0;
      while (__hip_atomic_load(ctr, __ATOMIC_ACQUIRE, __HIP_MEMORY_SCOPE_AGENT) < target) {
        __builtin_amdgcn_s_sleep(2);
        if (++guard > 400000000L) break;   // safety: fail visibly, never hang
      }
    }
    __syncthreads();
  }
}

// ---------------- launch -------------------------------------------------
extern "C" void kernel_launch(void* const* d_in, const int* in_sizes, int n_in,
                              void* d_out, int out_size, void* d_ws, size_t ws_size,
                              hipStream_t stream) {
  (void)in_sizes; (void)n_in; (void)out_size; (void)ws_size;
  const float* img   = (const float*)d_in[1];
  const int*   tgt   = (const int*)d_in[2];
  const float* emb   = (const float*)d_in[3];
  const float* W_in  = (const float*)d_in[4];
  const float* W_rec = (const float*)d_in[5];
  const float* b_l   = (const float*)d_in[6];
  const float* W_out = (const float*)d_in[7];
  const float* b_o   = (const float*)d_in[8];
  float* out = (float*)d_out;
  float* ws  = (float*)d_ws;

  float* zin = ws;                                     // 4,194,304 f
  float* rm  = ws + 4194304;                           //    65,536 f
  unsigned int* ctr = (unsigned int*)(ws + 4259840);   // 16 f reserved
  unsigned short* us = (unsigned short*)(ws + 4259856);
  unsigned short* x_bf  = us;                          // 1,048,576
  unsigned short* WinT  = us + 1048576;                // 1,048,576
  unsigned short* rnn   = us + 2097152;                // 1,048,576
  unsigned short* WrTh  = us + 3145728;                // 1,048,576
  unsigned short* WrTl  = us + 4194304;                // 1,048,576
  unsigned short* Abuf  = us + 5242880;                //   262,144 (2 x (hi+lo))
  unsigned short* WoutT = us + 5505024;                // 16,384,000  (~61 MB total)

  hipMemsetAsync(Abuf, 0, 131072 * sizeof(unsigned short), stream);  // parity-0 h0=0
  hipMemsetAsync(ctr, 0, 64, stream);

  build_x_kernel<<<4096, 256, 0, stream>>>(img, tgt, emb, x_bf);
  rec_mask_kernel<<<256, 256, 0, stream>>>(rm);
  transpose_cvt<<<dim3(64, 16), 256, 0, stream>>>(W_in, WinT, 512, 2048);
  transpose_split<<<dim3(64, 16), 256, 0, stream>>>(W_rec, WrTh, WrTl, 512, 2048);
  transpose_cvt<<<dim3(1000, 16), 256, 0, stream>>>(W_out, WoutT, 512, 32000);

  // z_in = x @ W_in + b_lstm : (2048x512)@(512x2048)
  gemm_bf16_mfma<<<dim3(16, 16), 256, 0, stream>>>(x_bf, WinT, b_l, zin, 2048, 2048);

  // all 64 LSTM steps in one persistent launch
  lstm_persistent<<<LSTM_BLOCKS, 256, 0, stream>>>(zin, WrTh, WrTl, rm, Abuf, rnn, ctr);

  // predictions = rnn_out @ W_out + b_out : (2048x512)@(512x32000)
  gemm_bf16_mfma<<<dim3(16, 250), 256, 0, stream>>>(rnn, WoutT, b_o, out, 2048, 32000);
}